// Round 11
// baseline (53.628 us; speedup 1.0000x reference)
//
#include <hip/hip_runtime.h>

#define H 128
#define W 128
#define C 64
#define HW (H * W)
#define RAD 2
#define KD 5

#define TS 8              // 8x8 pixel tile
#define HROWS 12          // halo rows (y0-2 .. y0+9)
#define RSTR 20           // u32 row stride (16 used cols + 4 pad -> 8-phase banks)
#define PSTR 244          // 12*20=240 +4 (keeps 16B align, shifts plane phase)
#define RPAIRS 16         // channel-pairs staged per round
#define LDSU (RPAIRS * PSTR) // 3904 u32 = 15.25 KB -> 8 blocks/CU

#define SCALE_L2E 0.18033688011112042f  // (1/sqrt(64)) * log2(e)

typedef _Float16 h2 __attribute__((ext_vector_type(2)));
typedef __fp16 fp16v2 __attribute__((ext_vector_type(2)));

__device__ __forceinline__ float dot2acc(h2 a, h2 w, float acc)
{
#if __has_builtin(__builtin_amdgcn_fdot2)
    return __builtin_amdgcn_fdot2(a, w, acc, false);   // v_dot2_f32_f16
#else
    return fmaf((float)a.x, (float)w.x, fmaf((float)a.y, (float)w.y, acc));
#endif
}

__device__ __forceinline__ uint32_t pkh2(float lo, float hi)
{
#if __has_builtin(__builtin_amdgcn_cvt_pkrtz)
    fp16v2 t = __builtin_amdgcn_cvt_pkrtz(lo, hi);
    return __builtin_bit_cast(uint32_t, t);
#else
    h2 t; t.x = (_Float16)lo; t.y = (_Float16)hi;
    return __builtin_bit_cast(uint32_t, t);
#endif
}

__device__ __forceinline__ h2 bch2(uint32_t u) { return __builtin_bit_cast(h2, u); }

// reduce across the 8 tap-groups: tg = lane bits 3..5
__device__ __forceinline__ float tg_reduce(float x)
{
    x += __shfl_xor(x, 8, 64);
    x += __shfl_xor(x, 16, 64);
    x += __shfl_xor(x, 32, 64);
    return x;
}

__global__ __launch_bounds__(256, 8)
void bam_corr_softmax_kernel(const float* __restrict__ f0,
                             const float* __restrict__ f1,
                             const float* __restrict__ f2,
                             float* __restrict__ out)
{
    __shared__ uint32_t lds[LDSU];

    const int tid  = threadIdx.x;
    const int lane = tid & 63;
    const int wav  = tid >> 6;         // 0..3
    const int tg   = lane >> 3;        // tap group 0..7
    const int slot = lane & 7;         // pixel-pair slot within wave
    const int lx   = (slot & 3) * 2;   // local x of first output (even)
    const int ly   = wav * 2 + (slot >> 2); // local y 0..7

    // XCD banding: band = blockIdx.x % 8 -> 16-row y-band per XCD L2 (~3.1MB);
    // consecutive blocks on an XCD cycle the 8 (v,b) jobs of the same tile.
    const int i     = blockIdx.x;
    const int band  = i & 7;
    const int j     = i >> 3;
    const int img   = j & 7;           // v*2 + b
    const int t     = j >> 3;          // 0..31
    const int tileX = t & 15;          // 0..15
    const int tileY = band * 2 + (t >> 4); // 0..15

    const int v = img >> 1;
    const int b = img & 1;

    const float* A;
    const float* Bf;
    if (v == 0)      { A = f0; Bf = f2; }
    else if (v == 1) { A = f1; Bf = f2; }
    else if (v == 2) { A = f2; Bf = f0; }
    else             { A = f2; Bf = f1; }

    const int x0 = tileX * TS;
    const int y0 = tileY * TS;
    const int x  = x0 + lx;
    const int y  = y0 + ly;

    const float* Arow  = A + (size_t)b * C * HW + (size_t)(y * W + x);
    const float* Bbase = Bf + (size_t)b * C * HW;

    const bool interior = (tileX >= 1) && (tileX <= 14) && (tileY >= 1) && (tileY <= 14);

    // ---- per-tap LDS dword offsets (k = tg + 8*i, clamped; dup taps masked in tail)
    int off[4];
#pragma unroll
    for (int ii = 0; ii < 4; ++ii) {
        int kraw = tg + 8 * ii;
        int k  = kraw > 24 ? 24 : kraw;
        int ky = (k * 13) >> 6;        // k/5 for k<=24
        int kx = k - 5 * ky;
        off[ii] = (ly + ky) * RSTR + lx + 2 + kx;
    }

    float c0[4] = {0.f, 0.f, 0.f, 0.f};
    float c1[4] = {0.f, 0.f, 0.f, 0.f};

    for (int r = 0; r < 2; ++r) {
        if (r) __syncthreads();        // compute(r-1) done before LDS overwrite

        // ---- stage 16 pair-planes (12 rows x 16 cols) as f16-pair uint4 ----
        // 16 planes * 12 rows * 4 chunks = 768 = 3 per thread exactly
#pragma unroll
        for (int it = 0; it < 3; ++it) {
            int q   = tid + it * 256;
            int p   = q / 48;          // plane-in-round 0..15
            int rem = q - p * 48;
            int row = rem >> 2;
            int c4  = rem & 3;
            int gy  = y0 - 2 + row;
            int gx  = x0 - 4 + c4 * 4;
            int ch0 = 2 * (r * RPAIRS + p);
            float4 lo, hi;
            if (interior) {
                const float* p0 = Bbase + (size_t)ch0 * HW + (size_t)(gy * W + gx);
                lo = *reinterpret_cast<const float4*>(p0);
                hi = *reinterpret_cast<const float4*>(p0 + HW);
            } else {
                float lv[4], hv[4];
#pragma unroll
                for (int e = 0; e < 4; ++e) {
                    int gxe = gx + e;
                    bool ok = (gy >= 0) && (gy < H) && (gxe >= 0) && (gxe < W);
                    size_t offg = (size_t)ch0 * HW + (size_t)(ok ? gy * W + gxe : 0);
                    lv[e] = ok ? Bbase[offg] : 0.f;
                    hv[e] = ok ? Bbase[offg + HW] : 0.f;
                }
                lo = make_float4(lv[0], lv[1], lv[2], lv[3]);
                hi = make_float4(hv[0], hv[1], hv[2], hv[3]);
            }
            uint4 wq = make_uint4(pkh2(lo.x, hi.x), pkh2(lo.y, hi.y),
                                  pkh2(lo.z, hi.z), pkh2(lo.w, hi.w));
            *reinterpret_cast<uint4*>(&lds[p * PSTR + row * RSTR + c4 * 4]) = wq;
        }
        __syncthreads();

        // ---- compute: all 16 pairs this round, ~4 taps per thread ----
#pragma unroll
        for (int p = 0; p < RPAIRS; ++p) {
            int P = r * RPAIRS + p;
            const float* ap = Arow + (size_t)(2 * P) * HW;
            float2 alo = *reinterpret_cast<const float2*>(ap);       // ch 2P   @ x,x+1
            float2 ahi = *reinterpret_cast<const float2*>(ap + HW);  // ch 2P+1 @ x,x+1
            h2 a0 = bch2(pkh2(alo.x, ahi.x));
            h2 a1 = bch2(pkh2(alo.y, ahi.y));
            const uint32_t* pb = &lds[p * PSTR];
#pragma unroll
            for (int ii = 0; ii < 4; ++ii) {
                uint32_t w0 = pb[off[ii]];       // adjacent -> ds_read2_b32
                uint32_t w1 = pb[off[ii] + 1];
                c0[ii] = dot2acc(a0, bch2(w0), c0[ii]);
                c1[ii] = dot2acc(a1, bch2(w1), c1[ii]);
            }
        }
    }

    // ---- per-tap exp + partial expectation sums, then 3-step tg reduce ----
    float sum0 = 0.f, ox0 = 0.f, oy0 = 0.f;
    float sum1 = 0.f, ox1 = 0.f, oy1 = 0.f;
#pragma unroll
    for (int ii = 0; ii < 4; ++ii) {
        int kraw = tg + 8 * ii;
        int k  = kraw > 24 ? 24 : kraw;
        int ky = (k * 13) >> 6;
        int kx = k - 5 * ky;
        float fx = (float)(kx - RAD);
        float fy = (float)(ky - RAD);
        bool tapok = kraw <= 24;
        bool ok0, ok1;
        if (interior) {
            ok0 = tapok; ok1 = tapok;
        } else {
            int syy = y + ky - RAD;
            bool py = (syy >= 0) && (syy < H);
            int sxx = x + kx - RAD;
            ok0 = tapok && py && (sxx >= 0) && (sxx < W);
            ok1 = tapok && py && (sxx + 1 >= 0) && (sxx + 1 < W);
        }
        float e0 = ok0 ? exp2f(c0[ii] * SCALE_L2E) : 0.f;
        float e1 = ok1 ? exp2f(c1[ii] * SCALE_L2E) : 0.f;
        sum0 += e0; ox0 += e0 * fx; oy0 += e0 * fy;
        sum1 += e1; ox1 += e1 * fx; oy1 += e1 * fy;
    }

    sum0 = tg_reduce(sum0); ox0 = tg_reduce(ox0); oy0 = tg_reduce(oy0);
    sum1 = tg_reduce(sum1); ox1 = tg_reduce(ox1); oy1 = tg_reduce(oy1);

    if (tg == 0) {
        float i0 = 1.f / sum0, i1 = 1.f / sum1;
        size_t ob = ((size_t)img * 2) * HW + (size_t)(y * W + x);
        *reinterpret_cast<float2*>(&out[ob])      = make_float2(ox0 * i0, ox1 * i1);
        *reinterpret_cast<float2*>(&out[ob + HW]) = make_float2(oy0 * i0, oy1 * i1);
    }
}

extern "C" void kernel_launch(void* const* d_in, const int* in_sizes, int n_in,
                              void* d_out, int out_size, void* d_ws, size_t ws_size,
                              hipStream_t stream)
{
    const float* f0 = (const float*)d_in[0];
    const float* f1 = (const float*)d_in[1];
    const float* f2 = (const float*)d_in[2];
    float* out = (float*)d_out;

    dim3 block(256, 1, 1);
    dim3 grid(2048, 1, 1); // 8 bands x 8 img x 32 tiles of 8x8
    bam_corr_softmax_kernel<<<grid, block, 0, stream>>>(f0, f1, f2, out);
}